// Round 13
// baseline (157.364 us; speedup 1.0000x reference)
//
#include <hip/hip_runtime.h>

typedef unsigned short u16;
typedef unsigned int   u32;
typedef __attribute__((ext_vector_type(8))) short bf16x8;
typedef __attribute__((ext_vector_type(4))) float f32x4;

#define MFMA16(a,b,c) __builtin_amdgcn_mfma_f32_16x16x32_bf16((a),(b),(c),0,0,0)
#define GLD16(gp, lp) __builtin_amdgcn_global_load_lds((const __attribute__((address_space(1))) u32*)(gp), (__attribute__((address_space(3))) u32*)(lp), 16, 0, 0)

#define B_   2
#define NG_  8
#define LS_  512
#define E_   1024
#define NH_  16
#define HD_  64
#define NTOK 8192   // B_*NG_*LS_

__device__ __forceinline__ u16 f2bu(float f){
  u32 u = __builtin_bit_cast(u32, f);
  u32 r = u + 0x7FFFu + ((u >> 16) & 1u);   // RN-even
  return (u16)(r >> 16);
}
__device__ __forceinline__ float b2f(u16 h){
  u32 u = ((u32)h) << 16;
  return __builtin_bit_cast(float, u);
}
__device__ __forceinline__ u32 pk2(float lo, float hi){   // 2x f32 -> packed bf16 (RNE)
  u32 r; asm("v_cvt_pk_bf16_f32 %0, %1, %2" : "=v"(r) : "v"(lo), "v"(hi)); return r;
}

// ---------------- merged prep: x->bf16 | Wqkv^T | Wproj^T | RoPE table ----------------
__global__ __launch_bounds__(256) void k_prep(const float* __restrict__ x, u16* __restrict__ xb,
                                              const float* __restrict__ Wqkv, u16* __restrict__ wqkvT,
                                              const float* __restrict__ Wproj, u16* __restrict__ wprojT,
                                              float* __restrict__ ct, float* __restrict__ st){
  int b = blockIdx.x;
  if (b < 8192){
    int i = b * 256 + threadIdx.x;
    float4 v = ((const float4*)x)[i];
    ((ushort4*)xb)[i] = make_ushort4(f2bu(v.x), f2bu(v.y), f2bu(v.z), f2bu(v.w));
    return;
  }
  if (b < 12288){
    const float* W; u16* WT; int Nd, bl;
    if (b < 11264){ W = Wqkv;  WT = wqkvT;  Nd = 3072; bl = b - 8192;  }
    else          { W = Wproj; WT = wprojT; Nd = 1024; bl = b - 11264; }
    int nbx = Nd >> 5;
    int bx = bl % nbx, by = bl / nbx;
    __shared__ float tile[32][33];
    int tx = threadIdx.x & 31, ty = threadIdx.x >> 5;
    int c0 = bx * 32, r0 = by * 32;
    #pragma unroll
    for (int i = 0; i < 4; i++)
      tile[ty + i*8][tx] = W[(size_t)(r0 + ty + i*8) * Nd + c0 + tx];
    __syncthreads();
    #pragma unroll
    for (int i = 0; i < 4; i++)
      WT[(size_t)(c0 + ty + i*8) * 1024 + r0 + tx] = f2bu(tile[tx][ty + i*8]);
    return;
  }
  {
    int i = (b - 12288) * 256 + threadIdx.x;   // 32768
    int s = i >> 6, d = i & 63, j = d & 31;
    float freq = powf(10000.f, -(4.f * (float)j + 1.f) / 64.f);
    float th = (float)s * freq;
    ct[i] = cosf(th);
    st[i] = sinf(th);
  }
}

// ---------------- T2+T4+T5 bf16 GEMM (round-9 proven, two-phase): C = A * Bt^T ----------------
// 128x128 tile, BK=64, LDS dbuf 64 KiB (2 blocks/CU), counted vmcnt(8), raw s_barrier,
// XOR-swizzle (linear gload_lds dest + inv-swizzled global source).
// FUSE_VT: blocks with tn>=16 (v-columns of QKV) write straight to vt[head][d][s].
template <typename OutT, bool FUSE_VT>
__global__ __launch_bounds__(256, 2) void k_gemm_bt(const u16* __restrict__ A, const u16* __restrict__ Bt,
                                                    OutT* __restrict__ C, u16* __restrict__ vt,
                                                    int M, int N, int K){
  int nbn = N >> 7;
  int cpx = gridDim.x >> 3;
  int bid = (blockIdx.x & 7) * cpx + (blockIdx.x >> 3);   // bijective XCD swizzle (grid%8==0)
  int tm = bid / nbn, tn = bid % nbn;
  int tid = threadIdx.x;
  int w = tid >> 6, l = tid & 63;
  int lr = l & 15, lg = l >> 4;
  int wm = (w >> 1) * 64, wn = (w & 1) * 64;

  __shared__ u16 smem[2][2][128 * 64];   // [buf][A/B] = 64 KiB total

  const u16* Ab = A  + (size_t)(tm * 128) * K;
  const u16* Bb = Bt + (size_t)(tn * 128) * K;
  int NT = K >> 6;                        // 16 for K=1024

  int srow0 = tid >> 3, ssl = tid & 7;
  auto stage = [&](int t, int s){
    int k0 = t << 6;
    #pragma unroll
    for (int q = 0; q < 4; q++){
      int row = q * 32 + srow0;
      int sc  = (ssl ^ (row & 7)) << 3;
      GLD16(Ab + (size_t)row * K + k0 + sc, &smem[s][0][q * 2048 + tid * 8]);
    }
    #pragma unroll
    for (int q = 0; q < 4; q++){
      int row = q * 32 + srow0;
      int sc  = (ssl ^ (row & 7)) << 3;
      GLD16(Bb + (size_t)row * K + k0 + sc, &smem[s][1][q * 2048 + tid * 8]);
    }
  };

  f32x4 acc[4][4] = {};

  stage(0, 0);
  stage(1, 1);
  asm volatile("s_waitcnt vmcnt(8)" ::: "memory");   // tile 0 landed, tile 1 in flight
  asm volatile("s_barrier" ::: "memory");

  for (int t = 0; t < NT; t++){
    int s = t & 1;
    const u16* As = smem[s][0];
    const u16* Bs = smem[s][1];
    bf16x8 bfr[4][2], afr[2][2];
    #pragma unroll
    for (int j = 0; j < 4; j++){
      int rb = wn + j * 16 + lr;
      #pragma unroll
      for (int kk = 0; kk < 2; kk++)
        bfr[j][kk] = *(const bf16x8*)&Bs[rb * 64 + ((kk * 32 + lg * 8) ^ ((rb & 7) << 3))];
    }
    #pragma unroll
    for (int i = 0; i < 2; i++){
      int ra = wm + i * 16 + lr;
      #pragma unroll
      for (int kk = 0; kk < 2; kk++)
        afr[i][kk] = *(const bf16x8*)&As[ra * 64 + ((kk * 32 + lg * 8) ^ ((ra & 7) << 3))];
    }
    __builtin_amdgcn_s_setprio(1);
    #pragma unroll
    for (int i = 0; i < 2; i++)
      #pragma unroll
      for (int j = 0; j < 4; j++){
        acc[i][j] = MFMA16(afr[i][0], bfr[j][0], acc[i][j]);
        acc[i][j] = MFMA16(afr[i][1], bfr[j][1], acc[i][j]);
      }
    __builtin_amdgcn_s_setprio(0);
    asm volatile("s_barrier" ::: "memory");
    #pragma unroll
    for (int i = 0; i < 2; i++){
      int ra = wm + (i + 2) * 16 + lr;
      #pragma unroll
      for (int kk = 0; kk < 2; kk++)
        afr[i][kk] = *(const bf16x8*)&As[ra * 64 + ((kk * 32 + lg * 8) ^ ((ra & 7) << 3))];
    }
    __builtin_amdgcn_s_setprio(1);
    #pragma unroll
    for (int i = 0; i < 2; i++)
      #pragma unroll
      for (int j = 0; j < 4; j++){
        acc[i + 2][j] = MFMA16(afr[i][0], bfr[j][0], acc[i + 2][j]);
        acc[i + 2][j] = MFMA16(afr[i][1], bfr[j][1], acc[i + 2][j]);
      }
    __builtin_amdgcn_s_setprio(0);
    asm volatile("s_barrier" ::: "memory");   // all waves done reading buf s
    if (t + 2 < NT){
      stage(t + 2, s);
      asm volatile("s_waitcnt vmcnt(8)" ::: "memory");
      asm volatile("s_barrier" ::: "memory");
    } else if (t + 2 == NT){
      asm volatile("s_waitcnt vmcnt(0)" ::: "memory");
      asm volatile("s_barrier" ::: "memory");
    }
  }

  if constexpr (FUSE_VT){
    if (tn >= 16){
      int h  = (tn - 16) * 2 + (wn >> 6);        // wave-uniform
      int bg = tm >> 2;
      u16* vbase = vt + (size_t)(bg * 16 + h) * HD_ * LS_;
      #pragma unroll
      for (int i = 0; i < 4; i++){
        int s0 = (tm & 3) * 128 + wm + i * 16 + lg * 4;
        #pragma unroll
        for (int j = 0; j < 4; j++){
          int d = j * 16 + lr;
          ushort4 pk = make_ushort4(f2bu(acc[i][j][0]), f2bu(acc[i][j][1]),
                                    f2bu(acc[i][j][2]), f2bu(acc[i][j][3]));
          *(ushort4*)&vbase[(size_t)d * LS_ + s0] = pk;
        }
      }
      return;
    }
  }

  #pragma unroll
  for (int i = 0; i < 4; i++)
    #pragma unroll
    for (int j = 0; j < 4; j++)
      #pragma unroll
      for (int r = 0; r < 4; r++){
        int row = tm * 128 + wm + i * 16 + lg * 4 + r;
        int col = tn * 128 + wn + j * 16 + lr;
        float v = acc[i][j][r];
        if constexpr (sizeof(OutT) == 2) C[(size_t)row * N + col] = f2bu(v);
        else                             C[(size_t)row * N + col] = v;
      }
}

// ---------------- RMSNorm + ln_w + RoPE + head split, q&k only (q scaled by 1/8) ----------------
__global__ __launch_bounds__(256) void k_norm_rope(const u16* __restrict__ qkv, const float* __restrict__ lnw,
                                                   const float* __restrict__ ct, const float* __restrict__ st,
                                                   u16* __restrict__ qh, u16* __restrict__ kh){
  int tok = blockIdx.x;
  int t = threadIdx.x;
  int s = tok & (LS_ - 1);
  int bg = tok >> 9;
  const u16* row = qkv + (size_t)tok * 3072;
  int e0 = t * 4;

  ushort4 q4 = *(const ushort4*)&row[e0];
  ushort4 k4 = *(const ushort4*)&row[1024 + e0];
  float qf[4] = {b2f(q4.x), b2f(q4.y), b2f(q4.z), b2f(q4.w)};
  float kf[4] = {b2f(k4.x), b2f(k4.y), b2f(k4.z), b2f(k4.w)};

  float qss = 0.f, kss = 0.f;
  #pragma unroll
  for (int j = 0; j < 4; j++){ qss += qf[j]*qf[j]; kss += kf[j]*kf[j]; }
  #pragma unroll
  for (int o = 32; o; o >>= 1){ qss += __shfl_down(qss, o); kss += __shfl_down(kss, o); }
  __shared__ float redq[4], redk[4];
  if ((t & 63) == 0){ redq[t >> 6] = qss; redk[t >> 6] = kss; }
  __syncthreads();
  float qsum = redq[0] + redq[1] + redq[2] + redq[3];
  float ksum = redk[0] + redk[1] + redk[2] + redk[3];
  float qr = rsqrtf(qsum * (1.f / 1024.f) + 1e-6f);
  float kr = rsqrtf(ksum * (1.f / 1024.f) + 1e-6f);

  float qn[4], kn[4];
  #pragma unroll
  for (int j = 0; j < 4; j++){
    float wv = lnw[e0 + j];
    qn[j] = qf[j] * qr * wv;
    kn[j] = kf[j] * kr * wv;
  }
  int d0 = e0 & 63, h = e0 >> 6;
  const float* cr = ct + s * 64 + d0;
  const float* sr = st + s * 64 + d0;
  float qo[4], ko[4];
  #pragma unroll
  for (int p = 0; p < 4; p += 2){
    float c0 = cr[p], s0 = sr[p], c1 = cr[p+1], s1 = sr[p+1];
    qo[p]   = qn[p]   * c0 - qn[p+1] * s0;
    qo[p+1] = qn[p+1] * c1 + qn[p]   * s1;
    ko[p]   = kn[p]   * c0 - kn[p+1] * s0;
    ko[p+1] = kn[p+1] * c1 + kn[p]   * s1;
  }
  size_t oidx = (((size_t)bg * NH_ + h) * LS_ + s) * HD_ + d0;
  *(ushort4*)&qh[oidx] = make_ushort4(f2bu(qo[0]*0.125f), f2bu(qo[1]*0.125f), f2bu(qo[2]*0.125f), f2bu(qo[3]*0.125f));
  *(ushort4*)&kh[oidx] = make_ushort4(f2bu(ko[0]), f2bu(ko[1]), f2bu(ko[2]), f2bu(ko[3]));
}

// ---------------- causal flash attention: 1-wave blocks, KVBLK=128, in-reg softmax ----------------
// KVBLK=128 halves the count of per-tile fixed costs (shuffle reduces, defer-check,
// P LDS round-trip, setprio toggles): 72 -> 40 tiles/head, at +11% masked-MFMA work.
__global__ __launch_bounds__(64) void k_attn(const u16* __restrict__ qh, const u16* __restrict__ kh,
                                             const u16* __restrict__ vt, u16* __restrict__ ytok){
  int bid = blockIdx.x;
  int head = bid & 255;
  int j = 15 - (bid >> 8);              // heavy jobs dispatched first
  int l = threadIdx.x & 63;
  int lr = l & 15, lg = l >> 4;
  int q0 = j * 32;
  int ntw = (j + 4) >> 2;               // KV-tiles of width 128 (exact)

  const u16* Qp = qh + (size_t)head * LS_ * HD_;
  const u16* Kp = kh + (size_t)head * LS_ * HD_;
  const u16* Vp = vt + (size_t)head * HD_ * LS_;   // [d][s]
  int bg = head >> 4, h = head & 15;
  u16* Yb = ytok + (size_t)bg * LS_ * E_ + h * HD_;

  bf16x8 aq[2][2];
  #pragma unroll
  for (int mi = 0; mi < 2; mi++)
    #pragma unroll
    for (int kk = 0; kk < 2; kk++)
      aq[mi][kk] = *(const bf16x8*)&Qp[(q0 + mi*16 + lr) * 64 + kk * 32 + lg * 8];

  __shared__ u16 Pw[32 * 136];          // per-wave P relayout buffer [q][kv=128], padded

  f32x4 o[2][4] = {};
  float mrun[2] = {-1e30f, -1e30f}, lrun[2] = {0.f, 0.f};

  for (int tkv = 0; tkv < ntw; tkv++){
    int kv0 = tkv * 128;
    // S^T = K Q^T : lane gets q=q0+mi*16+lr, kv=kv0+nk*16+lg*4+r, nk=0..7
    f32x4 sa[2][8] = {};
    __builtin_amdgcn_s_setprio(1);
    #pragma unroll
    for (int nk = 0; nk < 8; nk++){
      bf16x8 k0 = *(const bf16x8*)&Kp[(kv0 + nk*16 + lr) * 64 + lg * 8];
      bf16x8 k1 = *(const bf16x8*)&Kp[(kv0 + nk*16 + lr) * 64 + 32 + lg * 8];
      #pragma unroll
      for (int mi = 0; mi < 2; mi++){
        sa[mi][nk] = MFMA16(k0, aq[mi][0], sa[mi][nk]);
        sa[mi][nk] = MFMA16(k1, aq[mi][1], sa[mi][nk]);
      }
    }
    __builtin_amdgcn_s_setprio(0);
    // causal mask (last tile always; earlier tiles fully visible)
    if (kv0 + 127 > q0){
      #pragma unroll
      for (int mi = 0; mi < 2; mi++){
        int qg = q0 + mi*16 + lr;
        #pragma unroll
        for (int nk = 0; nk < 8; nk++)
          #pragma unroll
          for (int r = 0; r < 4; r++){
            int kg = kv0 + nk*16 + lg*4 + r;
            if (kg > qg) sa[mi][nk][r] = -1e30f;
          }
      }
    }
    float pmax[2];
    #pragma unroll
    for (int mi = 0; mi < 2; mi++){
      float pm = sa[mi][0][0];
      #pragma unroll
      for (int nk = 0; nk < 8; nk++)
        #pragma unroll
        for (int r = 0; r < 4; r++) pm = fmaxf(pm, sa[mi][nk][r]);
      pm = fmaxf(pm, __shfl_xor(pm, 16));
      pm = fmaxf(pm, __shfl_xor(pm, 32));
      pmax[mi] = pm;
    }
    float dm = fmaxf(pmax[0] - mrun[0], pmax[1] - mrun[1]);
    if (!__all(dm <= 8.f)){
      float alpha[2];
      #pragma unroll
      for (int mi = 0; mi < 2; mi++){
        float mnew = fmaxf(mrun[mi], pmax[mi]);
        alpha[mi] = __expf(mrun[mi] - mnew);
        mrun[mi] = mnew;
        lrun[mi] *= alpha[mi];
      }
      #pragma unroll
      for (int r = 0; r < 4; r++){
        float a0 = __shfl(alpha[0], lg * 4 + r);
        float a1 = __shfl(alpha[1], lg * 4 + r);
        #pragma unroll
        for (int nd = 0; nd < 4; nd++){ o[0][nd][r] *= a0; o[1][nd][r] *= a1; }
      }
    }
    #pragma unroll
    for (int mi = 0; mi < 2; mi++){
      float psum = 0.f;
      #pragma unroll
      for (int nk = 0; nk < 8; nk++)
        #pragma unroll
        for (int r = 0; r < 4; r++){
          float pv = __expf(sa[mi][nk][r] - mrun[mi]);
          sa[mi][nk][r] = pv;
          psum += pv;
        }
      psum += __shfl_xor(psum, 16);
      psum += __shfl_xor(psum, 32);
      lrun[mi] += psum;
    }
    // P (lane-local, kv-strided) -> per-wave LDS [q][kv] for A-fragment reads
    #pragma unroll
    for (int mi = 0; mi < 2; mi++)
      #pragma unroll
      for (int nk = 0; nk < 8; nk++){
        uint2 d01 = make_uint2(pk2(sa[mi][nk][0], sa[mi][nk][1]),
                               pk2(sa[mi][nk][2], sa[mi][nk][3]));
        *(uint2*)&Pw[(mi*16 + lr) * 136 + nk * 16 + lg * 4] = d01;
      }
    bf16x8 pa[2][4];
    #pragma unroll
    for (int mi = 0; mi < 2; mi++)
      #pragma unroll
      for (int kk = 0; kk < 4; kk++)
        pa[mi][kk] = *(const bf16x8*)&Pw[(mi*16 + lr) * 136 + kk * 32 + lg * 8];
    // O += P @ V
    __builtin_amdgcn_s_setprio(1);
    #pragma unroll
    for (int nd = 0; nd < 4; nd++)
      #pragma unroll
      for (int kk = 0; kk < 4; kk++){
        bf16x8 bv = *(const bf16x8*)&Vp[(nd*16 + lr) * 512 + kv0 + kk * 32 + lg * 8];
        #pragma unroll
        for (int mi = 0; mi < 2; mi++)
          o[mi][nd] = MFMA16(pa[mi][kk], bv, o[mi][nd]);
      }
    __builtin_amdgcn_s_setprio(0);
  }

  #pragma unroll
  for (int mi = 0; mi < 2; mi++){
    float linv = 1.f / lrun[mi];
    #pragma unroll
    for (int r = 0; r < 4; r++){
      float ir = __shfl(linv, lg * 4 + r);
      int qg = q0 + mi*16 + lg * 4 + r;
      #pragma unroll
      for (int nd = 0; nd < 4; nd++)
        Yb[(size_t)qg * E_ + nd * 16 + lr] = f2bu(o[mi][nd][r] * ir);
    }
  }
}

extern "C" void kernel_launch(void* const* d_in, const int* in_sizes, int n_in,
                              void* d_out, int out_size, void* d_ws, size_t ws_size,
                              hipStream_t stream){
  const float* x     = (const float*)d_in[0];
  const float* Wqkv  = (const float*)d_in[1];
  const float* lnw   = (const float*)d_in[2];
  const float* Wproj = (const float*)d_in[3];
  float* out = (float*)d_out;   // reference output dtype is float32

  u16* p = (u16*)d_ws;
  u16* xb     = p; p += (size_t)NTOK * E_;        // reused as ytok after GEMM1
  u16* wqkvT  = p; p += (size_t)3 * E_ * E_;
  u16* wprojT = p; p += (size_t)E_ * E_;
  u16* qkv    = p; p += (size_t)NTOK * 3 * E_;    // only q,k thirds written/read
  u16* qhp    = p; p += (size_t)NTOK * E_;
  u16* khp    = p; p += (size_t)NTOK * E_;
  u16* vtp    = p; p += (size_t)NTOK * E_;        // [head][d][s], written by GEMM1 epilogue
  float* ct = (float*)p;
  float* st = ct + LS_ * HD_;

  k_prep<<<12416, 256, 0, stream>>>(x, xb, Wqkv, wqkvT, Wproj, wprojT, ct, st);
  k_gemm_bt<u16, true><<<64 * 24, 256, 0, stream>>>(xb, wqkvT, qkv, vtp, NTOK, 3 * E_, E_);
  k_norm_rope<<<NTOK, 256, 0, stream>>>(qkv, lnw, ct, st, qhp, khp);
  k_attn<<<4096, 64, 0, stream>>>(qhp, khp, vtp, xb);            // xb now = y_tok
  k_gemm_bt<float, false><<<64 * 8, 256, 0, stream>>>(xb, wprojT, out, nullptr, NTOK, E_, E_);
}

// Round 14
// 150.134 us; speedup vs baseline: 1.0482x; 1.0482x over previous
//
#include <hip/hip_runtime.h>

typedef unsigned short u16;
typedef unsigned int   u32;
typedef __attribute__((ext_vector_type(8))) short bf16x8;
typedef __attribute__((ext_vector_type(4))) float f32x4;

#define MFMA16(a,b,c) __builtin_amdgcn_mfma_f32_16x16x32_bf16((a),(b),(c),0,0,0)
#define GLD16(gp, lp) __builtin_amdgcn_global_load_lds((const __attribute__((address_space(1))) u32*)(gp), (__attribute__((address_space(3))) u32*)(lp), 16, 0, 0)

#define B_   2
#define NG_  8
#define LS_  512
#define E_   1024
#define NH_  16
#define HD_  64
#define NTOK 8192   // B_*NG_*LS_

__device__ __forceinline__ u16 f2bu(float f){
  u32 u = __builtin_bit_cast(u32, f);
  u32 r = u + 0x7FFFu + ((u >> 16) & 1u);   // RN-even
  return (u16)(r >> 16);
}
__device__ __forceinline__ float b2f(u16 h){
  u32 u = ((u32)h) << 16;
  return __builtin_bit_cast(float, u);
}
__device__ __forceinline__ u32 pk2(float lo, float hi){   // 2x f32 -> packed bf16 (RNE)
  u32 r; asm("v_cvt_pk_bf16_f32 %0, %1, %2" : "=v"(r) : "v"(lo), "v"(hi)); return r;
}

// ---------------- merged prep: x->bf16 | Wqkv^T | Wproj^T | RoPE table ----------------
__global__ __launch_bounds__(256) void k_prep(const float* __restrict__ x, u16* __restrict__ xb,
                                              const float* __restrict__ Wqkv, u16* __restrict__ wqkvT,
                                              const float* __restrict__ Wproj, u16* __restrict__ wprojT,
                                              float* __restrict__ ct, float* __restrict__ st){
  int b = blockIdx.x;
  if (b < 8192){
    int i = b * 256 + threadIdx.x;
    float4 v = ((const float4*)x)[i];
    ((ushort4*)xb)[i] = make_ushort4(f2bu(v.x), f2bu(v.y), f2bu(v.z), f2bu(v.w));
    return;
  }
  if (b < 12288){
    const float* W; u16* WT; int Nd, bl;
    if (b < 11264){ W = Wqkv;  WT = wqkvT;  Nd = 3072; bl = b - 8192;  }
    else          { W = Wproj; WT = wprojT; Nd = 1024; bl = b - 11264; }
    int nbx = Nd >> 5;
    int bx = bl % nbx, by = bl / nbx;
    __shared__ float tile[32][33];
    int tx = threadIdx.x & 31, ty = threadIdx.x >> 5;
    int c0 = bx * 32, r0 = by * 32;
    #pragma unroll
    for (int i = 0; i < 4; i++)
      tile[ty + i*8][tx] = W[(size_t)(r0 + ty + i*8) * Nd + c0 + tx];
    __syncthreads();
    #pragma unroll
    for (int i = 0; i < 4; i++)
      WT[(size_t)(c0 + ty + i*8) * 1024 + r0 + tx] = f2bu(tile[tx][ty + i*8]);
    return;
  }
  {
    int i = (b - 12288) * 256 + threadIdx.x;   // 32768
    int s = i >> 6, d = i & 63, j = d & 31;
    float freq = powf(10000.f, -(4.f * (float)j + 1.f) / 64.f);
    float th = (float)s * freq;
    ct[i] = cosf(th);
    st[i] = sinf(th);
  }
}

// ---------------- T2+T4+T5 bf16 GEMM (two-phase) + L2 supertile order: C = A * Bt^T ----------------
// 128x128 tile, BK=64, LDS dbuf 64 KiB (2 blocks/CU), counted vmcnt(8), raw s_barrier,
// XOR-swizzle (linear gload_lds dest + inv-swizzled global source).
// XCD swizzle + 4x6 supertile ordering within XCD (when nbn%6==0): concurrent blocks
// share one 1.5MB B-chunk + ~3MB A-chunks -> L2-resident, kills B-panel refetch.
// FUSE_VT: blocks with tn>=16 (v-columns of QKV) write straight to vt[head][d][s].
template <typename OutT, bool FUSE_VT>
__global__ __launch_bounds__(256, 2) void k_gemm_bt(const u16* __restrict__ A, const u16* __restrict__ Bt,
                                                    OutT* __restrict__ C, u16* __restrict__ vt,
                                                    int M, int N, int K){
  int nbn = N >> 7;
  int cpx = gridDim.x >> 3;
  int xcd = blockIdx.x & 7;
  int ii  = blockIdx.x >> 3;              // [0, cpx) within this XCD
  int rpx = cpx / nbn;                    // tm-rows owned by this XCD
  int tm, tn;
  if ((nbn % 6) == 0 && (rpx & 3) == 0){  // 4x6 supertile (GEMM1: rpx=12, nbn=24)
    int st = ii / 24, wi = ii % 24;       // supertile id, index within
    int srn = rpx >> 2;                   // supertile-rows per XCD
    int sr = st % srn, sc = st / srn;     // sr-fastest: B-chunk reused across sr
    tm = xcd * rpx + sr * 4 + (wi / 6);
    tn = sc * 6 + (wi % 6);
  } else {
    int bid = xcd * cpx + ii;
    tm = bid / nbn; tn = bid % nbn;
  }
  int tid = threadIdx.x;
  int w = tid >> 6, l = tid & 63;
  int lr = l & 15, lg = l >> 4;
  int wm = (w >> 1) * 64, wn = (w & 1) * 64;

  __shared__ u16 smem[2][2][128 * 64];   // [buf][A/B] = 64 KiB total

  const u16* Ab = A  + (size_t)(tm * 128) * K;
  const u16* Bb = Bt + (size_t)(tn * 128) * K;
  int NT = K >> 6;                        // 16 for K=1024

  int srow0 = tid >> 3, ssl = tid & 7;
  auto stage = [&](int t, int s){
    int k0 = t << 6;
    #pragma unroll
    for (int q = 0; q < 4; q++){
      int row = q * 32 + srow0;
      int sc2 = (ssl ^ (row & 7)) << 3;
      GLD16(Ab + (size_t)row * K + k0 + sc2, &smem[s][0][q * 2048 + tid * 8]);
    }
    #pragma unroll
    for (int q = 0; q < 4; q++){
      int row = q * 32 + srow0;
      int sc2 = (ssl ^ (row & 7)) << 3;
      GLD16(Bb + (size_t)row * K + k0 + sc2, &smem[s][1][q * 2048 + tid * 8]);
    }
  };

  f32x4 acc[4][4] = {};

  stage(0, 0);
  stage(1, 1);
  asm volatile("s_waitcnt vmcnt(8)" ::: "memory");   // tile 0 landed, tile 1 in flight
  asm volatile("s_barrier" ::: "memory");

  for (int t = 0; t < NT; t++){
    int s = t & 1;
    const u16* As = smem[s][0];
    const u16* Bs = smem[s][1];
    bf16x8 bfr[4][2], afr[2][2];
    #pragma unroll
    for (int j = 0; j < 4; j++){
      int rb = wn + j * 16 + lr;
      #pragma unroll
      for (int kk = 0; kk < 2; kk++)
        bfr[j][kk] = *(const bf16x8*)&Bs[rb * 64 + ((kk * 32 + lg * 8) ^ ((rb & 7) << 3))];
    }
    #pragma unroll
    for (int i = 0; i < 2; i++){
      int ra = wm + i * 16 + lr;
      #pragma unroll
      for (int kk = 0; kk < 2; kk++)
        afr[i][kk] = *(const bf16x8*)&As[ra * 64 + ((kk * 32 + lg * 8) ^ ((ra & 7) << 3))];
    }
    __builtin_amdgcn_s_setprio(1);
    #pragma unroll
    for (int i = 0; i < 2; i++)
      #pragma unroll
      for (int j = 0; j < 4; j++){
        acc[i][j] = MFMA16(afr[i][0], bfr[j][0], acc[i][j]);
        acc[i][j] = MFMA16(afr[i][1], bfr[j][1], acc[i][j]);
      }
    __builtin_amdgcn_s_setprio(0);
    asm volatile("s_barrier" ::: "memory");
    #pragma unroll
    for (int i = 0; i < 2; i++){
      int ra = wm + (i + 2) * 16 + lr;
      #pragma unroll
      for (int kk = 0; kk < 2; kk++)
        afr[i][kk] = *(const bf16x8*)&As[ra * 64 + ((kk * 32 + lg * 8) ^ ((ra & 7) << 3))];
    }
    __builtin_amdgcn_s_setprio(1);
    #pragma unroll
    for (int i = 0; i < 2; i++)
      #pragma unroll
      for (int j = 0; j < 4; j++){
        acc[i + 2][j] = MFMA16(afr[i][0], bfr[j][0], acc[i + 2][j]);
        acc[i + 2][j] = MFMA16(afr[i][1], bfr[j][1], acc[i + 2][j]);
      }
    __builtin_amdgcn_s_setprio(0);
    asm volatile("s_barrier" ::: "memory");   // all waves done reading buf s
    if (t + 2 < NT){
      stage(t + 2, s);
      asm volatile("s_waitcnt vmcnt(8)" ::: "memory");
      asm volatile("s_barrier" ::: "memory");
    } else if (t + 2 == NT){
      asm volatile("s_waitcnt vmcnt(0)" ::: "memory");
      asm volatile("s_barrier" ::: "memory");
    }
  }

  if constexpr (FUSE_VT){
    if (tn >= 16){
      int h  = (tn - 16) * 2 + (wn >> 6);        // wave-uniform
      int bg = tm >> 2;
      u16* vbase = vt + (size_t)(bg * 16 + h) * HD_ * LS_;
      #pragma unroll
      for (int i = 0; i < 4; i++){
        int s0 = (tm & 3) * 128 + wm + i * 16 + lg * 4;
        #pragma unroll
        for (int j = 0; j < 4; j++){
          int d = j * 16 + lr;
          ushort4 pk = make_ushort4(f2bu(acc[i][j][0]), f2bu(acc[i][j][1]),
                                    f2bu(acc[i][j][2]), f2bu(acc[i][j][3]));
          *(ushort4*)&vbase[(size_t)d * LS_ + s0] = pk;
        }
      }
      return;
    }
  }

  #pragma unroll
  for (int i = 0; i < 4; i++)
    #pragma unroll
    for (int j = 0; j < 4; j++)
      #pragma unroll
      for (int r = 0; r < 4; r++){
        int row = tm * 128 + wm + i * 16 + lg * 4 + r;
        int col = tn * 128 + wn + j * 16 + lr;
        float v = acc[i][j][r];
        if constexpr (sizeof(OutT) == 2) C[(size_t)row * N + col] = f2bu(v);
        else                             C[(size_t)row * N + col] = v;
      }
}

// ---------------- RMSNorm + ln_w + RoPE + head split, q&k only (q scaled by 1/8) ----------------
__global__ __launch_bounds__(256) void k_norm_rope(const u16* __restrict__ qkv, const float* __restrict__ lnw,
                                                   const float* __restrict__ ct, const float* __restrict__ st,
                                                   u16* __restrict__ qh, u16* __restrict__ kh){
  int tok = blockIdx.x;
  int t = threadIdx.x;
  int s = tok & (LS_ - 1);
  int bg = tok >> 9;
  const u16* row = qkv + (size_t)tok * 3072;
  int e0 = t * 4;

  ushort4 q4 = *(const ushort4*)&row[e0];
  ushort4 k4 = *(const ushort4*)&row[1024 + e0];
  float qf[4] = {b2f(q4.x), b2f(q4.y), b2f(q4.z), b2f(q4.w)};
  float kf[4] = {b2f(k4.x), b2f(k4.y), b2f(k4.z), b2f(k4.w)};

  float qss = 0.f, kss = 0.f;
  #pragma unroll
  for (int j = 0; j < 4; j++){ qss += qf[j]*qf[j]; kss += kf[j]*kf[j]; }
  #pragma unroll
  for (int o = 32; o; o >>= 1){ qss += __shfl_down(qss, o); kss += __shfl_down(kss, o); }
  __shared__ float redq[4], redk[4];
  if ((t & 63) == 0){ redq[t >> 6] = qss; redk[t >> 6] = kss; }
  __syncthreads();
  float qsum = redq[0] + redq[1] + redq[2] + redq[3];
  float ksum = redk[0] + redk[1] + redk[2] + redk[3];
  float qr = rsqrtf(qsum * (1.f / 1024.f) + 1e-6f);
  float kr = rsqrtf(ksum * (1.f / 1024.f) + 1e-6f);

  float qn[4], kn[4];
  #pragma unroll
  for (int j = 0; j < 4; j++){
    float wv = lnw[e0 + j];
    qn[j] = qf[j] * qr * wv;
    kn[j] = kf[j] * kr * wv;
  }
  int d0 = e0 & 63, h = e0 >> 6;
  const float* cr = ct + s * 64 + d0;
  const float* sr = st + s * 64 + d0;
  float qo[4], ko[4];
  #pragma unroll
  for (int p = 0; p < 4; p += 2){
    float c0 = cr[p], s0 = sr[p], c1 = cr[p+1], s1 = sr[p+1];
    qo[p]   = qn[p]   * c0 - qn[p+1] * s0;
    qo[p+1] = qn[p+1] * c1 + qn[p]   * s1;
    ko[p]   = kn[p]   * c0 - kn[p+1] * s0;
    ko[p+1] = kn[p+1] * c1 + kn[p]   * s1;
  }
  size_t oidx = (((size_t)bg * NH_ + h) * LS_ + s) * HD_ + d0;
  *(ushort4*)&qh[oidx] = make_ushort4(f2bu(qo[0]*0.125f), f2bu(qo[1]*0.125f), f2bu(qo[2]*0.125f), f2bu(qo[3]*0.125f));
  *(ushort4*)&kh[oidx] = make_ushort4(f2bu(ko[0]), f2bu(ko[1]), f2bu(ko[2]), f2bu(ko[3]));
}

// ---------------- causal flash attention: 1-wave blocks, KVBLK=64, in-reg softmax ----------------
__global__ __launch_bounds__(64) void k_attn(const u16* __restrict__ qh, const u16* __restrict__ kh,
                                             const u16* __restrict__ vt, u16* __restrict__ ytok){
  int bid = blockIdx.x;
  int head = bid & 255;
  int j = 15 - (bid >> 8);              // heavy jobs dispatched first
  int l = threadIdx.x & 63;
  int lr = l & 15, lg = l >> 4;
  int q0 = j * 32;
  int ntw = (j >> 1) + 1;               // exact KV-tile count

  const u16* Qp = qh + (size_t)head * LS_ * HD_;
  const u16* Kp = kh + (size_t)head * LS_ * HD_;
  const u16* Vp = vt + (size_t)head * HD_ * LS_;   // [d][s]
  int bg = head >> 4, h = head & 15;
  u16* Yb = ytok + (size_t)bg * LS_ * E_ + h * HD_;

  bf16x8 aq[2][2];
  #pragma unroll
  for (int mi = 0; mi < 2; mi++)
    #pragma unroll
    for (int kk = 0; kk < 2; kk++)
      aq[mi][kk] = *(const bf16x8*)&Qp[(q0 + mi*16 + lr) * 64 + kk * 32 + lg * 8];

  __shared__ u16 Pw[32 * 72];           // per-wave P relayout buffer (1 wave/block)

  f32x4 o[2][4] = {};
  float mrun[2] = {-1e30f, -1e30f}, lrun[2] = {0.f, 0.f};

  for (int tkv = 0; tkv < ntw; tkv++){
    int kv0 = tkv * 64;
    f32x4 sa[2][4] = {};
    __builtin_amdgcn_s_setprio(1);
    #pragma unroll
    for (int nk = 0; nk < 4; nk++){
      bf16x8 k0 = *(const bf16x8*)&Kp[(kv0 + nk*16 + lr) * 64 + lg * 8];
      bf16x8 k1 = *(const bf16x8*)&Kp[(kv0 + nk*16 + lr) * 64 + 32 + lg * 8];
      #pragma unroll
      for (int mi = 0; mi < 2; mi++){
        sa[mi][nk] = MFMA16(k0, aq[mi][0], sa[mi][nk]);
        sa[mi][nk] = MFMA16(k1, aq[mi][1], sa[mi][nk]);
      }
    }
    __builtin_amdgcn_s_setprio(0);
    if (kv0 + 63 > q0){
      #pragma unroll
      for (int mi = 0; mi < 2; mi++){
        int qg = q0 + mi*16 + lr;
        #pragma unroll
        for (int nk = 0; nk < 4; nk++)
          #pragma unroll
          for (int r = 0; r < 4; r++){
            int kg = kv0 + nk*16 + lg*4 + r;
            if (kg > qg) sa[mi][nk][r] = -1e30f;
          }
      }
    }
    float pmax[2];
    #pragma unroll
    for (int mi = 0; mi < 2; mi++){
      float pm = sa[mi][0][0];
      #pragma unroll
      for (int nk = 0; nk < 4; nk++)
        #pragma unroll
        for (int r = 0; r < 4; r++) pm = fmaxf(pm, sa[mi][nk][r]);
      pm = fmaxf(pm, __shfl_xor(pm, 16));
      pm = fmaxf(pm, __shfl_xor(pm, 32));
      pmax[mi] = pm;
    }
    float dm = fmaxf(pmax[0] - mrun[0], pmax[1] - mrun[1]);
    if (!__all(dm <= 8.f)){
      float alpha[2];
      #pragma unroll
      for (int mi = 0; mi < 2; mi++){
        float mnew = fmaxf(mrun[mi], pmax[mi]);
        alpha[mi] = __expf(mrun[mi] - mnew);
        mrun[mi] = mnew;
        lrun[mi] *= alpha[mi];
      }
      #pragma unroll
      for (int r = 0; r < 4; r++){
        float a0 = __shfl(alpha[0], lg * 4 + r);
        float a1 = __shfl(alpha[1], lg * 4 + r);
        #pragma unroll
        for (int nd = 0; nd < 4; nd++){ o[0][nd][r] *= a0; o[1][nd][r] *= a1; }
      }
    }
    #pragma unroll
    for (int mi = 0; mi < 2; mi++){
      float psum = 0.f;
      #pragma unroll
      for (int nk = 0; nk < 4; nk++)
        #pragma unroll
        for (int r = 0; r < 4; r++){
          float pv = __expf(sa[mi][nk][r] - mrun[mi]);
          sa[mi][nk][r] = pv;
          psum += pv;
        }
      psum += __shfl_xor(psum, 16);
      psum += __shfl_xor(psum, 32);
      lrun[mi] += psum;
    }
    #pragma unroll
    for (int mi = 0; mi < 2; mi++)
      #pragma unroll
      for (int nk = 0; nk < 4; nk++){
        *(u32*)&Pw[(mi*16 + lr) * 72 + nk * 16 + lg * 4]     = pk2(sa[mi][nk][0], sa[mi][nk][1]);
        *(u32*)&Pw[(mi*16 + lr) * 72 + nk * 16 + lg * 4 + 2] = pk2(sa[mi][nk][2], sa[mi][nk][3]);
      }
    bf16x8 pa[2][2];
    #pragma unroll
    for (int mi = 0; mi < 2; mi++){
      pa[mi][0] = *(const bf16x8*)&Pw[(mi*16 + lr) * 72 + lg * 8];
      pa[mi][1] = *(const bf16x8*)&Pw[(mi*16 + lr) * 72 + 32 + lg * 8];
    }
    __builtin_amdgcn_s_setprio(1);
    #pragma unroll
    for (int nd = 0; nd < 4; nd++){
      bf16x8 bv0 = *(const bf16x8*)&Vp[(nd*16 + lr) * 512 + kv0 + lg * 8];
      bf16x8 bv1 = *(const bf16x8*)&Vp[(nd*16 + lr) * 512 + kv0 + 32 + lg * 8];
      #pragma unroll
      for (int mi = 0; mi < 2; mi++){
        o[mi][nd] = MFMA16(pa[mi][0], bv0, o[mi][nd]);
        o[mi][nd] = MFMA16(pa[mi][1], bv1, o[mi][nd]);
      }
    }
    __builtin_amdgcn_s_setprio(0);
  }

  #pragma unroll
  for (int mi = 0; mi < 2; mi++){
    float linv = 1.f / lrun[mi];
    #pragma unroll
    for (int r = 0; r < 4; r++){
      float ir = __shfl(linv, lg * 4 + r);
      int qg = q0 + mi*16 + lg * 4 + r;
      #pragma unroll
      for (int nd = 0; nd < 4; nd++)
        Yb[(size_t)qg * E_ + nd * 16 + lr] = f2bu(o[mi][nd][r] * ir);
    }
  }
}

extern "C" void kernel_launch(void* const* d_in, const int* in_sizes, int n_in,
                              void* d_out, int out_size, void* d_ws, size_t ws_size,
                              hipStream_t stream){
  const float* x     = (const float*)d_in[0];
  const float* Wqkv  = (const float*)d_in[1];
  const float* lnw   = (const float*)d_in[2];
  const float* Wproj = (const float*)d_in[3];
  float* out = (float*)d_out;   // reference output dtype is float32

  u16* p = (u16*)d_ws;
  u16* xb     = p; p += (size_t)NTOK * E_;        // reused as ytok after GEMM1
  u16* wqkvT  = p; p += (size_t)3 * E_ * E_;
  u16* wprojT = p; p += (size_t)E_ * E_;
  u16* qkv    = p; p += (size_t)NTOK * 3 * E_;    // only q,k thirds written/read
  u16* qhp    = p; p += (size_t)NTOK * E_;
  u16* khp    = p; p += (size_t)NTOK * E_;
  u16* vtp    = p; p += (size_t)NTOK * E_;        // [head][d][s], written by GEMM1 epilogue
  float* ct = (float*)p;
  float* st = ct + LS_ * HD_;

  k_prep<<<12416, 256, 0, stream>>>(x, xb, Wqkv, wqkvT, Wproj, wprojT, ct, st);
  k_gemm_bt<u16, true><<<64 * 24, 256, 0, stream>>>(xb, wqkvT, qkv, vtp, NTOK, 3 * E_, E_);
  k_norm_rope<<<NTOK, 256, 0, stream>>>(qkv, lnw, ct, st, qhp, khp);
  k_attn<<<4096, 64, 0, stream>>>(qhp, khp, vtp, xb);            // xb now = y_tok
  k_gemm_bt<float, false><<<64 * 8, 256, 0, stream>>>(xb, wprojT, out, nullptr, NTOK, E_, E_);
}